// Round 7
// baseline (339.984 us; speedup 1.0000x reference)
//
#include <hip/hip_runtime.h>
#include <stdint.h>

#define DIM     128
#define NMEM    16384
#define NQ_TOT  2048
#define TQ      64                    // queries per WG
#define TN      64                    // mem rows per iter
#define NTILES_TOT (NMEM / TN)        // 256
#define QROWS   (NQ_TOT / TQ)         // 32
#define SHIFT   30.0f

typedef short s8v __attribute__((ext_vector_type(8)));
typedef float f4v __attribute__((ext_vector_type(4)));

// ---- workspace layout (bytes) ----
#define OFF_MHI   0u
#define OFF_MHIT  (4u << 20)
#define OFF_ML8   (8u << 20)
#define OFF_NUM   (12u << 20)
#define NUM_BYTES(c)  ((uint32_t)(c) * NQ_TOT * DIM * 4u)      // 1 MB per chunk
#define OFF_DEN(c)    (OFF_NUM + NUM_BYTES(c))
#define WS_NEED(c)    ((size_t)(OFF_DEN(c) + (uint32_t)(c) * NQ_TOT * 4u))

__device__ __forceinline__ uint16_t f2bf(float x) {
    uint32_t u = __float_as_uint(x);
    uint32_t r = u + 0x7fffu + ((u >> 16) & 1u);   // RNE
    return (uint16_t)(r >> 16);
}
__device__ __forceinline__ float bf2f(uint16_t h) {
    return __uint_as_float(((uint32_t)h) << 16);
}
// OCP e4m3fn, RNE, FTZ below 2^-6, saturate to 448.
__device__ __forceinline__ uint32_t f2e4m3(float x) {
    const uint32_t u = __float_as_uint(x);
    const uint32_t s = (u >> 31) << 7;
    const uint32_t a = u & 0x7fffffffu;
    if (a < 0x3c800000u) return s;
    const uint32_t r = u + 0x7ffffu + ((u >> 20) & 1u);
    const uint32_t e = (r >> 23) & 0xffu;
    uint32_t code = ((e - 120u) << 3) | ((r >> 20) & 7u);
    if (code > 0x7eu) code = 0x7eu;
    return s | code;
}

// ==== pre-pass: fp32 memory -> bf16 hi (row), e4m3 lo*256 (row), bf16 hi^T ====
__global__ __launch_bounds__(256)
void convert_kernel(const float* __restrict__ mem, uint16_t* __restrict__ mhi,
                    uint16_t* __restrict__ mhit, uint8_t* __restrict__ ml8) {
    __shared__ uint16_t T[DIM * 64];           // [d][n] 16 KB
    const int b  = blockIdx.x;                 // 256 blocks x 64 rows
    const int t  = threadIdx.x;
    const int n0 = b * 64;
    #pragma unroll
    for (int k = 0; k < 8; ++k) {
        const int idx4 = t + k * 256;
        const int r    = idx4 >> 5;
        const int c4   = idx4 & 31;
        const float4 v = ((const float4*)(mem + (size_t)(n0 + r) * DIM))[c4];
        const uint16_t h0 = f2bf(v.x), h1 = f2bf(v.y), h2 = f2bf(v.z), h3 = f2bf(v.w);
        *(ushort4*)&mhi[(size_t)(n0 + r) * DIM + c4 * 4] = make_ushort4(h0, h1, h2, h3);
        const uint32_t pk = f2e4m3((v.x - bf2f(h0)) * 256.f)
                          | (f2e4m3((v.y - bf2f(h1)) * 256.f) << 8)
                          | (f2e4m3((v.z - bf2f(h2)) * 256.f) << 16)
                          | (f2e4m3((v.w - bf2f(h3)) * 256.f) << 24);
        *(uint32_t*)&ml8[(size_t)(n0 + r) * DIM + c4 * 4] = pk;
        T[(c4 * 4 + 0) * 64 + r] = h0;
        T[(c4 * 4 + 1) * 64 + r] = h1;
        T[(c4 * 4 + 2) * 64 + r] = h2;
        T[(c4 * 4 + 3) * 64 + r] = h3;
    }
    __syncthreads();
    #pragma unroll
    for (int p = 0; p < 4; ++p) {
        const int d    = (t >> 3) + p * 32;
        const int part = t & 7;
        *(uint4*)&mhit[(size_t)d * NMEM + n0 + part * 8] =
            *(const uint4*)&T[d * 64 + part * 8];
    }
}

// ==== main attention: R4 synchronous-burst structure, fp8 M-lo, 3 blocks/CU ==
// QK = qh*mh + ql*mh (bf16) + q8*ml8/256 (fp8). XCD-pinned chunks (bx&7).
// LDS 49.4KB -> 3 blocks/CU when grid = 32 qrows x NCHK=24 chunks = 768.
template <int NCHK>
__global__ __launch_bounds__(256, 2)
void attn_kernel(const float* __restrict__ query,
                 const uint16_t* __restrict__ mhi,
                 const uint16_t* __restrict__ mhit,
                 const uint8_t* __restrict__ ml8g,
                 float* __restrict__ num, float* __restrict__ den) {
    __shared__ uint16_t MsHi[TN * DIM];     // 16 KB
    __shared__ uint8_t  Ml8 [TN * DIM];     // 8 KB
    __shared__ uint16_t MsT [DIM * TN];     // 16 KB
    __shared__ uint16_t Ps  [TQ * TN];      // 8 KB
    __shared__ float    Red [4 * TQ];       // 1 KB

    const int tid   = threadIdx.x;
    const int wv    = tid >> 6;
    const int lane  = tid & 63;
    const int l16   = lane & 15;
    const int quad  = lane >> 4;
    const int bx    = blockIdx.x;
    // XCD-affinity: NCHK/8 chunks pinned per XCD
    constexpr int CPX = NCHK / 8;
    const int xcd   = bx & 7;
    const int j     = bx >> 3;
    const int chunk = xcd * CPX + (j % CPX);
    const int qrow  = j / CPX;                 // 0..31
    const int q0    = qrow * TQ;
    // uneven tile split: 256 tiles over NCHK chunks
    constexpr int BASE = NTILES_TOT / NCHK;
    constexpr int REM  = NTILES_TOT % NCHK;
    const int tile0  = chunk * BASE + (chunk < REM ? chunk : REM);
    const int ntiles = BASE + (chunk < REM ? 1 : 0);

    // ---- Q fragments: bf16 hi/lo + fp8, resident in registers ----
    s8v qh[4][4], ql[4][4];
    long q8[4][4];
    #pragma unroll
    for (int qt = 0; qt < 4; ++qt) {
        const float* qp = query + (size_t)(q0 + qt * 16 + l16) * DIM + quad * 8;
        #pragma unroll
        for (int ks = 0; ks < 4; ++ks) {
            const float4 a = *(const float4*)(qp + ks * 32);
            const float4 b = *(const float4*)(qp + ks * 32 + 4);
            const float f[8] = {a.x, a.y, a.z, a.w, b.x, b.y, b.z, b.w};
            s8v vh, vl;
            #pragma unroll
            for (int jj = 0; jj < 8; ++jj) {
                const uint16_t hh = f2bf(f[jj]);
                vh[jj] = (short)hh;
                vl[jj] = (short)f2bf(f[jj] - bf2f(hh));
            }
            qh[qt][ks] = vh;
            ql[qt][ks] = vl;
            const uint32_t lo = f2e4m3(f[0]) | (f2e4m3(f[1]) << 8)
                              | (f2e4m3(f[2]) << 16) | (f2e4m3(f[3]) << 24);
            const uint32_t hi = f2e4m3(f[4]) | (f2e4m3(f[5]) << 8)
                              | (f2e4m3(f[6]) << 16) | (f2e4m3(f[7]) << 24);
            q8[qt][ks] = (long)(((uint64_t)hi << 32) | (uint64_t)lo);
        }
    }

    f4v oacc[4][2];
    float dacc[16];
    #pragma unroll
    for (int qt = 0; qt < 4; ++qt)
        #pragma unroll
        for (int dt = 0; dt < 2; ++dt)
            oacc[qt][dt] = (f4v){0.f, 0.f, 0.f, 0.f};
    #pragma unroll
    for (int i = 0; i < 16; ++i) dacc[i] = 0.f;

    for (int it = 0; it < ntiles; ++it) {
        const int n0 = (tile0 + it) * TN;
        __syncthreads();                       // prev iter finished with tiles

        // ---- stage: 40 x 16B global_load_lds, 10 per wave (synchronous burst)
        #pragma unroll
        for (int ii = 0; ii < 10; ++ii) {
            const int id = wv * 10 + ii;
            if (id < 16) {                     // MsHi: 16 x 1KB
                const int s = id * 64 + lane;
                const int r = s >> 4, c = (s & 15) ^ (r & 7);
                const uint16_t* g = mhi + (size_t)(n0 + r) * DIM + c * 8;
                __builtin_amdgcn_global_load_lds(
                    (const __attribute__((address_space(1))) void*)g,
                    (__attribute__((address_space(3))) void*)&MsHi[id * 512], 16, 0, 0);
            } else if (id < 24) {              // Ml8: 8 x 1KB
                const int jj = id - 16;
                const int s = jj * 64 + lane;
                const int r = s >> 3, g = (s & 7) ^ (r & 7);
                const uint8_t* gp = ml8g + (size_t)(n0 + r) * DIM + g * 16;
                __builtin_amdgcn_global_load_lds(
                    (const __attribute__((address_space(1))) void*)gp,
                    (__attribute__((address_space(3))) void*)&Ml8[jj * 1024], 16, 0, 0);
            } else {                           // MsT: 16 x 1KB
                const int jj = id - 24;
                const int s = jj * 64 + lane;
                const int d = s >> 3, c = (s & 7) ^ (d & 7);
                const uint16_t* g = mhit + (size_t)d * NMEM + n0 + c * 8;
                __builtin_amdgcn_global_load_lds(
                    (const __attribute__((address_space(1))) void*)g,
                    (__attribute__((address_space(3))) void*)&MsT[jj * 512], 16, 0, 0);
            }
        }
        __syncthreads();                       // drain + visibility

        // ---- QK^T: wave wv owns rows [wv*16, wv*16+16) ----
        f4v sacc[4], cacc[4];
        #pragma unroll
        for (int qt = 0; qt < 4; ++qt) {
            sacc[qt] = (f4v){0.f, 0.f, 0.f, 0.f};
            cacc[qt] = (f4v){0.f, 0.f, 0.f, 0.f};
        }
        const int r   = wv * 16 + l16;
        const int rsw = r & 7;
        #pragma unroll
        for (int ks = 0; ks < 4; ++ks) {
            const int c = ks * 4 + quad;
            const s8v bh = *(const s8v*)&MsHi[r * DIM + ((c ^ rsw) << 3)];
            const int g16 = ks * 2 + (quad >> 1);
            const long b8 = *(const long*)&Ml8[r * DIM +
                                (((g16 ^ rsw) << 4) | ((quad & 1) << 3))];
            #pragma unroll
            for (int qt = 0; qt < 4; ++qt) {
                sacc[qt] = __builtin_amdgcn_mfma_f32_16x16x32_bf16(qh[qt][ks], bh, sacc[qt], 0, 0, 0);
                sacc[qt] = __builtin_amdgcn_mfma_f32_16x16x32_bf16(ql[qt][ks], bh, sacc[qt], 0, 0, 0);
                cacc[qt] = __builtin_amdgcn_mfma_f32_16x16x32_fp8_fp8(q8[qt][ks], b8, cacc[qt], 0, 0, 0);
            }
        }

        // ---- exp + P write (bf16, num/den consistent) ----
        const int ntl = wv * 16 + l16;
        const int nc = ntl >> 3, nlo = ntl & 7;
        #pragma unroll
        for (int qt = 0; qt < 4; ++qt)
            #pragma unroll
            for (int rg = 0; rg < 4; ++rg) {
                const float s = sacc[qt][rg] + cacc[qt][rg] * (1.0f / 256.0f);
                const float p = __expf(s - SHIFT);
                const uint16_t pb = f2bf(p);
                dacc[qt * 4 + rg] += bf2f(pb);
                const int qloc = qt * 16 + quad * 4 + rg;
                const int swz  = (qloc ^ (qloc >> 3)) & 7;
                Ps[qloc * TN + ((nc ^ swz) << 3) + nlo] = pb;
            }
        __syncthreads();                       // Ps visible to all waves

        // ---- PV: wave wv owns d in [wv*32, wv*32+32) ----
        #pragma unroll
        for (int ks = 0; ks < 2; ++ks) {
            s8v bt[2];
            #pragma unroll
            for (int dt = 0; dt < 2; ++dt) {
                const int d = wv * 32 + dt * 16 + l16;
                const int c = ks * 4 + quad;
                bt[dt] = *(const s8v*)&MsT[d * TN + ((c ^ (d & 7)) << 3)];
            }
            #pragma unroll
            for (int qt = 0; qt < 4; ++qt) {
                const int q   = qt * 16 + l16;
                const int swz = (q ^ (q >> 3)) & 7;
                const int c   = ks * 4 + quad;
                const s8v pf  = *(const s8v*)&Ps[q * TN + ((c ^ swz) << 3)];
                oacc[qt][0] = __builtin_amdgcn_mfma_f32_16x16x32_bf16(pf, bt[0], oacc[qt][0], 0, 0, 0);
                oacc[qt][1] = __builtin_amdgcn_mfma_f32_16x16x32_bf16(pf, bt[1], oacc[qt][1], 0, 0, 0);
            }
        }
    }

    // ---- epilogue: denominator cross-lane + cross-wave reduce ----
    #pragma unroll
    for (int m = 1; m <= 8; m <<= 1)
        #pragma unroll
        for (int i = 0; i < 16; ++i)
            dacc[i] += __shfl_xor(dacc[i], m, 64);
    if (l16 == 0) {
        #pragma unroll
        for (int qt = 0; qt < 4; ++qt)
            #pragma unroll
            for (int rg = 0; rg < 4; ++rg)
                Red[wv * TQ + qt * 16 + quad * 4 + rg] = dacc[qt * 4 + rg];
    }
    __syncthreads();
    if (tid < TQ) {
        const float dsum = Red[tid] + Red[TQ + tid] + Red[2 * TQ + tid] + Red[3 * TQ + tid];
        den[chunk * NQ_TOT + q0 + tid] = dsum;
    }
    // ---- numerator partial stores (R4-style direct) ----
    #pragma unroll
    for (int qt = 0; qt < 4; ++qt)
        #pragma unroll
        for (int dt = 0; dt < 2; ++dt)
            #pragma unroll
            for (int rg = 0; rg < 4; ++rg) {
                const int q = q0 + qt * 16 + quad * 4 + rg;
                const int d = wv * 32 + dt * 16 + l16;
                num[(size_t)chunk * NQ_TOT * DIM + (size_t)q * DIM + d] = oacc[qt][dt][rg];
            }
}

// ============ final reduce over chunks + normalize (float4) ============
template <int NCHK>
__global__ __launch_bounds__(256)
void reduce_kernel(const float* __restrict__ num, const float* __restrict__ den,
                   float* __restrict__ out) {
    const int f = blockIdx.x * 256 + threadIdx.x;   // 65536 float4s
    const int q = f >> 5;
    float4 ns = make_float4(0.f, 0.f, 0.f, 0.f);
    float ds = 0.f;
    #pragma unroll
    for (int c = 0; c < NCHK; ++c) {
        const float4 v = ((const float4*)num)[c * (NQ_TOT * DIM / 4) + f];
        ns.x += v.x; ns.y += v.y; ns.z += v.z; ns.w += v.w;
        ds += den[c * NQ_TOT + q];
    }
    const float inv = 1.0f / ds;
    ((float4*)out)[f] = make_float4(ns.x * inv, ns.y * inv, ns.z * inv, ns.w * inv);
}

// ============ fallback (round-1 fp32 kernel) if ws too small ============
#define FTQ 8
#define FTN 64
#define FNTILES (NMEM / FTN)
#define FBLOCK 512
#define MPAD 132
#define PPAD 68

__global__ __launch_bounds__(FBLOCK, 2)
void sparse_attn_fp32(const float* __restrict__ query,
                      const float* __restrict__ memory,
                      float* __restrict__ out) {
    __shared__ float Qs[FTQ * MPAD];
    __shared__ float Ms[FTN * MPAD];
    __shared__ float Psh[FTQ * PPAD];
    __shared__ float Rd[FTQ * PPAD];
    const int tid = threadIdx.x;
    const int q = tid & 7, rest = tid >> 3;
    const int ng = rest, dg = rest & 31, half = rest >> 5;
    const long q0 = (long)blockIdx.x * FTQ;
    if (tid < FTQ * DIM / 4) {
        const float4 v = ((const float4*)(query + q0 * DIM))[tid];
        *(float4*)&Qs[(tid >> 5) * MPAD + ((tid & 31) << 2)] = v;
    }
    float4 pf[4];
    {
        const float4* msrc = (const float4*)memory;
        #pragma unroll
        for (int k = 0; k < 4; ++k) pf[k] = msrc[tid + k * FBLOCK];
    }
    float4 acc = make_float4(0.f, 0.f, 0.f, 0.f);
    float l_part = 0.f;
    for (int t = 0; t < FNTILES; ++t) {
        __syncthreads();
        #pragma unroll
        for (int k = 0; k < 4; ++k) {
            const int f4 = tid + k * FBLOCK;
            *(float4*)&Ms[(f4 >> 5) * MPAD + ((f4 & 31) << 2)] = pf[k];
        }
        __syncthreads();
        if (t + 1 < FNTILES) {
            const float4* msrc = (const float4*)(memory + (long)(t + 1) * FTN * DIM);
            #pragma unroll
            for (int k = 0; k < 4; ++k) pf[k] = msrc[tid + k * FBLOCK];
        }
        float4 s4 = make_float4(0.f, 0.f, 0.f, 0.f);
        const float* qrow = &Qs[q * MPAD];
        const float* mrow = &Ms[ng * MPAD];
        #pragma unroll
        for (int jj = 0; jj < 32; ++jj) {
            const float4 qv = *(const float4*)&qrow[jj * 4];
            const float4 mv = *(const float4*)&mrow[jj * 4];
            s4.x += qv.x * mv.x; s4.y += qv.y * mv.y;
            s4.z += qv.z * mv.z; s4.w += qv.w * mv.w;
        }
        const float p = __expf(((s4.x + s4.y) + (s4.z + s4.w)) - SHIFT);
        Psh[q * PPAD + ng] = p;
        l_part += p;
        __syncthreads();
        #pragma unroll
        for (int n = 0; n < 32; ++n) {
            const int nn = half * 32 + n;
            const float pw = Psh[q * PPAD + nn];
            const float4 mv = *(const float4*)&Ms[nn * MPAD + dg * 4];
            acc.x += pw * mv.x; acc.y += pw * mv.y;
            acc.z += pw * mv.z; acc.w += pw * mv.w;
        }
    }
    __syncthreads();
    Rd[q * PPAD + rest] = l_part;
    if (half == 1) *(float4*)&Ms[q * MPAD + dg * 4] = acc;
    __syncthreads();
    if (half == 0) {
        const float4 o2 = *(const float4*)&Ms[q * MPAD + dg * 4];
        float l = 0.f;
        #pragma unroll 8
        for (int i = 0; i < 64; ++i) l += Rd[q * PPAD + i];
        const float inv = 1.0f / l;
        float4 o;
        o.x = (acc.x + o2.x) * inv; o.y = (acc.y + o2.y) * inv;
        o.z = (acc.z + o2.z) * inv; o.w = (acc.w + o2.w) * inv;
        *(float4*)(out + (q0 + q) * DIM + dg * 4) = o;
    }
}

extern "C" void kernel_launch(void* const* d_in, const int* in_sizes, int n_in,
                              void* d_out, int out_size, void* d_ws, size_t ws_size,
                              hipStream_t stream) {
    const float* query  = (const float*)d_in[0];
    const float* memory = (const float*)d_in[1];
    float* out = (float*)d_out;
    if (ws_size >= WS_NEED(16)) {
        uint16_t* mhi  = (uint16_t*)((char*)d_ws + OFF_MHI);
        uint16_t* mhit = (uint16_t*)((char*)d_ws + OFF_MHIT);
        uint8_t*  ml8  = (uint8_t*)((char*)d_ws + OFF_ML8);
        float*    num  = (float*)((char*)d_ws + OFF_NUM);
        convert_kernel<<<NMEM / 64, 256, 0, stream>>>(memory, mhi, mhit, ml8);
        if (ws_size >= WS_NEED(24)) {
            float* den = (float*)((char*)d_ws + OFF_DEN(24));
            attn_kernel<24><<<QROWS * 24, 256, 0, stream>>>(query, mhi, mhit, ml8, num, den);
            reduce_kernel<24><<<NQ_TOT * DIM / 4 / 256, 256, 0, stream>>>(num, den, out);
        } else {
            float* den = (float*)((char*)d_ws + OFF_DEN(16));
            attn_kernel<16><<<QROWS * 16, 256, 0, stream>>>(query, mhi, mhit, ml8, num, den);
            reduce_kernel<16><<<NQ_TOT * DIM / 4 / 256, 256, 0, stream>>>(num, den, out);
        }
    } else {
        sparse_attn_fp32<<<NQ_TOT / FTQ, FBLOCK, 0, stream>>>(query, memory, out);
    }
}

// Round 8
// 126.766 us; speedup vs baseline: 2.6820x; 2.6820x over previous
//
#include <hip/hip_runtime.h>
#include <stdint.h>

#define DIM     128
#define NMEM    16384
#define NQ_TOT  2048
#define TQ      128                   // queries per WG (q-split QK across waves)
#define TN      64                    // mem rows per iter
#define NTILES_TOT (NMEM / TN)        // 256
#define QROWS   (NQ_TOT / TQ)         // 16
#define SHIFT   30.0f
#define PSTR    72                    // Ps row stride (shorts): 144B, 16B-aligned

typedef short s8v __attribute__((ext_vector_type(8)));
typedef float f4v __attribute__((ext_vector_type(4)));

// ---- workspace layout (bytes) ----
#define OFF_MHI   0u
#define OFF_MLO   (4u << 20)
#define OFF_MHIT  (8u << 20)
#define OFF_NUM   (12u << 20)
#define NUM_BYTES(c)  ((uint32_t)(c) * NQ_TOT * DIM * 2u)   // bf16 partials
#define OFF_DEN(c)    (OFF_NUM + NUM_BYTES(c))
#define WS_NEED(c)    ((size_t)(OFF_DEN(c) + (uint32_t)(c) * NQ_TOT * 4u))

__device__ __forceinline__ uint16_t f2bf(float x) {
    uint32_t u = __float_as_uint(x);
    uint32_t r = u + 0x7fffu + ((u >> 16) & 1u);   // RNE
    return (uint16_t)(r >> 16);
}
__device__ __forceinline__ float bf2f(uint16_t h) {
    return __uint_as_float(((uint32_t)h) << 16);
}

// ============ pre-pass: fp32 memory -> bf16 hi/lo + transposed hi ============
__global__ __launch_bounds__(256)
void convert_kernel(const float* __restrict__ mem, uint16_t* __restrict__ mhi,
                    uint16_t* __restrict__ mlo, uint16_t* __restrict__ mhit) {
    __shared__ uint16_t T[DIM * 64];           // [d][n] 16 KB
    const int b  = blockIdx.x;                 // 256 blocks x 64 rows
    const int t  = threadIdx.x;
    const int n0 = b * 64;
    #pragma unroll
    for (int k = 0; k < 8; ++k) {
        const int idx4 = t + k * 256;
        const int r    = idx4 >> 5;
        const int c4   = idx4 & 31;
        const float4 v = ((const float4*)(mem + (size_t)(n0 + r) * DIM))[c4];
        const uint16_t h0 = f2bf(v.x), h1 = f2bf(v.y), h2 = f2bf(v.z), h3 = f2bf(v.w);
        *(ushort4*)&mhi[(size_t)(n0 + r) * DIM + c4 * 4] = make_ushort4(h0, h1, h2, h3);
        *(ushort4*)&mlo[(size_t)(n0 + r) * DIM + c4 * 4] =
            make_ushort4(f2bf(v.x - bf2f(h0)), f2bf(v.y - bf2f(h1)),
                         f2bf(v.z - bf2f(h2)), f2bf(v.w - bf2f(h3)));
        T[(c4 * 4 + 0) * 64 + r] = h0;
        T[(c4 * 4 + 1) * 64 + r] = h1;
        T[(c4 * 4 + 2) * 64 + r] = h2;
        T[(c4 * 4 + 3) * 64 + r] = h3;
    }
    __syncthreads();
    #pragma unroll
    for (int p = 0; p < 4; ++p) {
        const int d    = (t >> 3) + p * 32;
        const int part = t & 7;
        *(uint4*)&mhit[(size_t)d * NMEM + n0 + part * 8] =
            *(const uint4*)&T[d * 64 + part * 8];
    }
}

// ==== main attention: TQ=128, q-split QK, R4 numerics/staging, grid 512 ======
// Per-CU block-rounds halved vs R4 (32->16); staged traffic halved (196 MB).
// XCD pinning (bx&7) at the validated grid=512; 4 chunks/XCD = 1.5MB L2 set.
template <int NCHK>
__global__ __launch_bounds__(256, 2)
void attn_kernel(const float* __restrict__ query,
                 const uint16_t* __restrict__ mhi,
                 const uint16_t* __restrict__ mlo,
                 const uint16_t* __restrict__ mhit,
                 uint16_t* __restrict__ num, float* __restrict__ den) {
    // carved shared block: MsHi 8192 | MsLo 8192 | MsT 8192 | Ps 128*72 | Red
    __shared__ uint16_t SM[34048];             // 68096 B -> 2 blocks/CU
    uint16_t* MsHi = SM;                       // [n64][d-granule^swz]
    uint16_t* MsLo = SM + 8192;
    uint16_t* MsT  = SM + 16384;               // [d128][n-granule^swz]
    uint16_t* Ps   = SM + 24576;               // [q128][PSTR]
    float*    Red  = (float*)(SM + 33792);     // [128]

    const int tid   = threadIdx.x;
    const int wv    = tid >> 6;
    const int lane  = tid & 63;
    const int l16   = lane & 15;
    const int quad  = lane >> 4;
    const int bx    = blockIdx.x;
    constexpr int CPX = NCHK / 8;              // chunks pinned per XCD
    const int xcd   = bx & 7;
    const int j     = bx >> 3;
    const int chunk = xcd * CPX + (j % CPX);
    const int qrow  = j / CPX;                 // 0..QROWS-1
    const int q0    = qrow * TQ;
    constexpr int ITERS = NTILES_TOT / NCHK;
    const int nbase = chunk * (NMEM / NCHK);

    // ---- Q fragments for this wave's 32-query QK slice (bf16 hi/lo) ----
    s8v qh[2][4], ql[2][4];
    #pragma unroll
    for (int qt = 0; qt < 2; ++qt) {
        const float* qp = query + (size_t)(q0 + wv * 32 + qt * 16 + l16) * DIM + quad * 8;
        #pragma unroll
        for (int ks = 0; ks < 4; ++ks) {
            const float4 a = *(const float4*)(qp + ks * 32);
            const float4 b = *(const float4*)(qp + ks * 32 + 4);
            const float f[8] = {a.x, a.y, a.z, a.w, b.x, b.y, b.z, b.w};
            s8v vh, vl;
            #pragma unroll
            for (int jj = 0; jj < 8; ++jj) {
                const uint16_t hh = f2bf(f[jj]);
                vh[jj] = (short)hh;
                vl[jj] = (short)f2bf(f[jj] - bf2f(hh));
            }
            qh[qt][ks] = vh;
            ql[qt][ks] = vl;
        }
    }

    f4v oacc[8][2];                            // PV acc: 8 q-tiles x 2 d-tiles
    float dacc[8];                             // den partials: 2 qt x 4 rg
    #pragma unroll
    for (int qt = 0; qt < 8; ++qt) {
        oacc[qt][0] = (f4v){0.f, 0.f, 0.f, 0.f};
        oacc[qt][1] = (f4v){0.f, 0.f, 0.f, 0.f};
    }
    #pragma unroll
    for (int i = 0; i < 8; ++i) dacc[i] = 0.f;

    for (int it = 0; it < ITERS; ++it) {
        const int n0 = nbase + it * TN;
        __syncthreads();                       // prev iter done with tiles/Ps

        // ---- stage: 48 x 16B global_load_lds, 12 per wave (R4 pattern) ----
        #pragma unroll
        for (int ii = 0; ii < 12; ++ii) {
            const int id = wv * 12 + ii;
            if (id < 16) {
                const int s = id * 64 + lane;
                const int r = s >> 4, c = (s & 15) ^ (r & 7);
                const uint16_t* g = mhi + (size_t)(n0 + r) * DIM + c * 8;
                __builtin_amdgcn_global_load_lds(
                    (const __attribute__((address_space(1))) void*)g,
                    (__attribute__((address_space(3))) void*)&MsHi[id * 512], 16, 0, 0);
            } else if (id < 32) {
                const int jj = id - 16;
                const int s = jj * 64 + lane;
                const int r = s >> 4, c = (s & 15) ^ (r & 7);
                const uint16_t* g = mlo + (size_t)(n0 + r) * DIM + c * 8;
                __builtin_amdgcn_global_load_lds(
                    (const __attribute__((address_space(1))) void*)g,
                    (__attribute__((address_space(3))) void*)&MsLo[jj * 512], 16, 0, 0);
            } else {
                const int jj = id - 32;
                const int s = jj * 64 + lane;
                const int d = s >> 3, c = (s & 7) ^ (d & 7);
                const uint16_t* g = mhit + (size_t)d * NMEM + n0 + c * 8;
                __builtin_amdgcn_global_load_lds(
                    (const __attribute__((address_space(1))) void*)g,
                    (__attribute__((address_space(3))) void*)&MsT[jj * 512], 16, 0, 0);
            }
        }
        __syncthreads();                       // drain + visibility

        // ---- QK^T (q-split): wave wv computes S[q0+wv*32 .. +32][all 64 n] --
        f4v sacc[2][4];
        #pragma unroll
        for (int qt = 0; qt < 2; ++qt)
            #pragma unroll
            for (int nt = 0; nt < 4; ++nt)
                sacc[qt][nt] = (f4v){0.f, 0.f, 0.f, 0.f};
        #pragma unroll
        for (int nt = 0; nt < 4; ++nt) {
            const int r   = nt * 16 + l16;
            const int rsw = r & 7;
            #pragma unroll
            for (int ks = 0; ks < 4; ++ks) {
                const int c = ks * 4 + quad;
                const s8v bh = *(const s8v*)&MsHi[r * DIM + ((c ^ rsw) << 3)];
                const s8v bl = *(const s8v*)&MsLo[r * DIM + ((c ^ rsw) << 3)];
                #pragma unroll
                for (int qt = 0; qt < 2; ++qt) {
                    sacc[qt][nt] = __builtin_amdgcn_mfma_f32_16x16x32_bf16(qh[qt][ks], bh, sacc[qt][nt], 0, 0, 0);
                    sacc[qt][nt] = __builtin_amdgcn_mfma_f32_16x16x32_bf16(ql[qt][ks], bh, sacc[qt][nt], 0, 0, 0);
                    sacc[qt][nt] = __builtin_amdgcn_mfma_f32_16x16x32_bf16(qh[qt][ks], bl, sacc[qt][nt], 0, 0, 0);
                }
            }
        }

        // ---- exp + P write (bf16, num/den consistent) ----
        #pragma unroll
        for (int qt = 0; qt < 2; ++qt)
            #pragma unroll
            for (int nt = 0; nt < 4; ++nt)
                #pragma unroll
                for (int rg = 0; rg < 4; ++rg) {
                    const float p = __expf(sacc[qt][nt][rg] - SHIFT);
                    const uint16_t pb = f2bf(p);
                    dacc[qt * 4 + rg] += bf2f(pb);
                    const int qloc = wv * 32 + qt * 16 + quad * 4 + rg;
                    Ps[qloc * PSTR + nt * 16 + l16] = pb;
                }
        __syncthreads();                       // Ps visible to all waves

        // ---- PV (d-split): wave wv owns d in [wv*32, wv*32+32) ----
        #pragma unroll
        for (int ksP = 0; ksP < 2; ++ksP) {
            s8v bt[2];
            #pragma unroll
            for (int dt = 0; dt < 2; ++dt) {
                const int d  = wv * 32 + dt * 16 + l16;
                const int cg = ksP * 4 + quad;
                bt[dt] = *(const s8v*)&MsT[d * TN + ((cg ^ (d & 7)) << 3)];
            }
            #pragma unroll
            for (int qt = 0; qt < 8; ++qt) {
                const int q = qt * 16 + l16;
                const s8v pf = *(const s8v*)&Ps[q * PSTR + ksP * 32 + quad * 8];
                oacc[qt][0] = __builtin_amdgcn_mfma_f32_16x16x32_bf16(pf, bt[0], oacc[qt][0], 0, 0, 0);
                oacc[qt][1] = __builtin_amdgcn_mfma_f32_16x16x32_bf16(pf, bt[1], oacc[qt][1], 0, 0, 0);
            }
        }
    }

    // ---- denominator: reduce over l16 (each q lives in exactly one wave) ----
    #pragma unroll
    for (int m = 1; m <= 8; m <<= 1)
        #pragma unroll
        for (int i = 0; i < 8; ++i)
            dacc[i] += __shfl_xor(dacc[i], m, 64);
    __syncthreads();                           // loop done; SM reusable
    if (l16 == 0) {
        #pragma unroll
        for (int qt = 0; qt < 2; ++qt)
            #pragma unroll
            for (int rg = 0; rg < 4; ++rg)
                Red[wv * 32 + qt * 16 + quad * 4 + rg] = dacc[qt * 4 + rg];
    }
    // ---- O merge into LDS (bf16) for coalesced stores ----
    uint16_t* Obuf = SM;                       // 128 q x 128 d x 2B = 32 KB
    #pragma unroll
    for (int qt = 0; qt < 8; ++qt)
        #pragma unroll
        for (int dt = 0; dt < 2; ++dt)
            #pragma unroll
            for (int rg = 0; rg < 4; ++rg) {
                const int qq = qt * 16 + quad * 4 + rg;
                const int dd = wv * 32 + dt * 16 + l16;
                Obuf[qq * DIM + dd] = f2bf(oacc[qt][dt][rg]);
            }
    __syncthreads();
    if (tid < TQ) den[chunk * NQ_TOT + q0 + tid] = Red[tid];
    {
        uint4* dst = (uint4*)(num + ((size_t)chunk * NQ_TOT + q0) * DIM);
        const uint4* src = (const uint4*)Obuf;
        #pragma unroll
        for (int k = 0; k < 8; ++k) {
            const int f = tid + k * 256;       // 2048 uint4s (32 KB)
            dst[f] = src[f];
        }
    }
}

// ============ final reduce over chunks + normalize ============
template <int NCHK>
__global__ __launch_bounds__(256)
void reduce_kernel(const uint16_t* __restrict__ num, const float* __restrict__ den,
                   float* __restrict__ out) {
    const int f = blockIdx.x * 256 + threadIdx.x;   // 65536 groups of 4
    const int q = f >> 5;
    float4 ns = make_float4(0.f, 0.f, 0.f, 0.f);
    float ds = 0.f;
    #pragma unroll
    for (int c = 0; c < NCHK; ++c) {
        const ushort4 v = ((const ushort4*)num)[c * (NQ_TOT * DIM / 4) + f];
        ns.x += bf2f(v.x); ns.y += bf2f(v.y); ns.z += bf2f(v.z); ns.w += bf2f(v.w);
        ds += den[c * NQ_TOT + q];
    }
    const float inv = 1.0f / ds;
    ((float4*)out)[f] = make_float4(ns.x * inv, ns.y * inv, ns.z * inv, ns.w * inv);
}

// ============ fallback (round-1 fp32 kernel) if ws too small ============
#define FTQ 8
#define FTN 64
#define FNTILES (NMEM / FTN)
#define FBLOCK 512
#define MPAD 132
#define PPAD 68

__global__ __launch_bounds__(FBLOCK, 2)
void sparse_attn_fp32(const float* __restrict__ query,
                      const float* __restrict__ memory,
                      float* __restrict__ out) {
    __shared__ float Qs[FTQ * MPAD];
    __shared__ float Ms[FTN * MPAD];
    __shared__ float Psh[FTQ * PPAD];
    __shared__ float Rd[FTQ * PPAD];
    const int tid = threadIdx.x;
    const int q = tid & 7, rest = tid >> 3;
    const int ng = rest, dg = rest & 31, half = rest >> 5;
    const long q0 = (long)blockIdx.x * FTQ;
    if (tid < FTQ * DIM / 4) {
        const float4 v = ((const float4*)(query + q0 * DIM))[tid];
        *(float4*)&Qs[(tid >> 5) * MPAD + ((tid & 31) << 2)] = v;
    }
    float4 pf[4];
    {
        const float4* msrc = (const float4*)memory;
        #pragma unroll
        for (int k = 0; k < 4; ++k) pf[k] = msrc[tid + k * FBLOCK];
    }
    float4 acc = make_float4(0.f, 0.f, 0.f, 0.f);
    float l_part = 0.f;
    for (int t = 0; t < FNTILES; ++t) {
        __syncthreads();
        #pragma unroll
        for (int k = 0; k < 4; ++k) {
            const int f4 = tid + k * FBLOCK;
            *(float4*)&Ms[(f4 >> 5) * MPAD + ((f4 & 31) << 2)] = pf[k];
        }
        __syncthreads();
        if (t + 1 < FNTILES) {
            const float4* msrc = (const float4*)(memory + (long)(t + 1) * FTN * DIM);
            #pragma unroll
            for (int k = 0; k < 4; ++k) pf[k] = msrc[tid + k * FBLOCK];
        }
        float4 s4 = make_float4(0.f, 0.f, 0.f, 0.f);
        const float* qrow = &Qs[q * MPAD];
        const float* mrow = &Ms[ng * MPAD];
        #pragma unroll
        for (int jj = 0; jj < 32; ++jj) {
            const float4 qv = *(const float4*)&qrow[jj * 4];
            const float4 mv = *(const float4*)&mrow[jj * 4];
            s4.x += qv.x * mv.x; s4.y += qv.y * mv.y;
            s4.z += qv.z * mv.z; s4.w += qv.w * mv.w;
        }
        const float p = __expf(((s4.x + s4.y) + (s4.z + s4.w)) - SHIFT);
        Psh[q * PPAD + ng] = p;
        l_part += p;
        __syncthreads();
        #pragma unroll
        for (int n = 0; n < 32; ++n) {
            const int nn = half * 32 + n;
            const float pw = Psh[q * PPAD + nn];
            const float4 mv = *(const float4*)&Ms[nn * MPAD + dg * 4];
            acc.x += pw * mv.x; acc.y += pw * mv.y;
            acc.z += pw * mv.z; acc.w += pw * mv.w;
        }
    }
    __syncthreads();
    Rd[q * PPAD + rest] = l_part;
    if (half == 1) *(float4*)&Ms[q * MPAD + dg * 4] = acc;
    __syncthreads();
    if (half == 0) {
        const float4 o2 = *(const float4*)&Ms[q * MPAD + dg * 4];
        float l = 0.f;
        #pragma unroll 8
        for (int i = 0; i < 64; ++i) l += Rd[q * PPAD + i];
        const float inv = 1.0f / l;
        float4 o;
        o.x = (acc.x + o2.x) * inv; o.y = (acc.y + o2.y) * inv;
        o.z = (acc.z + o2.z) * inv; o.w = (acc.w + o2.w) * inv;
        *(float4*)(out + (q0 + q) * DIM + dg * 4) = o;
    }
}

extern "C" void kernel_launch(void* const* d_in, const int* in_sizes, int n_in,
                              void* d_out, int out_size, void* d_ws, size_t ws_size,
                              hipStream_t stream) {
    const float* query  = (const float*)d_in[0];
    const float* memory = (const float*)d_in[1];
    float* out = (float*)d_out;
    if (ws_size >= WS_NEED(16)) {
        uint16_t* mhi  = (uint16_t*)((char*)d_ws + OFF_MHI);
        uint16_t* mlo  = (uint16_t*)((char*)d_ws + OFF_MLO);
        uint16_t* mhit = (uint16_t*)((char*)d_ws + OFF_MHIT);
        uint16_t* num  = (uint16_t*)((char*)d_ws + OFF_NUM);
        convert_kernel<<<NMEM / 64, 256, 0, stream>>>(memory, mhi, mlo, mhit);
        if (ws_size >= WS_NEED(32)) {
            float* den = (float*)((char*)d_ws + OFF_DEN(32));
            attn_kernel<32><<<QROWS * 32, 256, 0, stream>>>(query, mhi, mlo, mhit, num, den);
            reduce_kernel<32><<<NQ_TOT * DIM / 4 / 256, 256, 0, stream>>>(num, den, out);
        } else {
            float* den = (float*)((char*)d_ws + OFF_DEN(16));
            attn_kernel<16><<<QROWS * 16, 256, 0, stream>>>(query, mhi, mlo, mhit, num, den);
            reduce_kernel<16><<<NQ_TOT * DIM / 4 / 256, 256, 0, stream>>>(num, den, out);
        }
    } else {
        sparse_attn_fp32<<<NQ_TOT / FTQ, FBLOCK, 0, stream>>>(query, memory, out);
    }
}

// Round 9
// 100.650 us; speedup vs baseline: 3.3779x; 1.2595x over previous
//
#include <hip/hip_runtime.h>
#include <stdint.h>

#define DIM     128
#define NMEM    16384
#define NQ_TOT  2048
#define TQ      128                   // queries per WG (q-split QK across waves)
#define TN      64                    // mem rows per iter
#define NTILES_TOT (NMEM / TN)        // 256
#define QROWS   (NQ_TOT / TQ)         // 16
#define SHIFT   30.0f
#define PSTR    72                    // Ps row stride (shorts): 144B, 16B-aligned

typedef short    s8v __attribute__((ext_vector_type(8)));
typedef _Float16 h8v __attribute__((ext_vector_type(8)));
typedef float    f4v __attribute__((ext_vector_type(4)));

// ---- workspace layout (bytes) ----
#define OFF_MF16  0u
#define OFF_MHIT  (4u << 20)
#define OFF_NUM   (8u << 20)
#define NUM_BYTES(c)  ((uint32_t)(c) * NQ_TOT * DIM * 2u)   // bf16 partials
#define OFF_DEN(c)    (OFF_NUM + NUM_BYTES(c))
#define WS_NEED(c)    ((size_t)(OFF_DEN(c) + (uint32_t)(c) * NQ_TOT * 4u))

__device__ __forceinline__ uint16_t f2bf(float x) {
    uint32_t u = __float_as_uint(x);
    uint32_t r = u + 0x7fffu + ((u >> 16) & 1u);   // RNE
    return (uint16_t)(r >> 16);
}
__device__ __forceinline__ float bf2f(uint16_t h) {
    return __uint_as_float(((uint32_t)h) << 16);
}
__device__ __forceinline__ uint16_t f2h(float x) {  // fp16 RNE via v_cvt_f16_f32
    union { _Float16 h; uint16_t u; } c;
    c.h = (_Float16)x;
    return c.u;
}

// ==== pre-pass: fp32 memory -> fp16 M (row-major) + bf16 M^T ====
__global__ __launch_bounds__(256)
void convert_kernel(const float* __restrict__ mem, uint16_t* __restrict__ mf16,
                    uint16_t* __restrict__ mhit) {
    __shared__ uint16_t T[DIM * 65];           // [d][n], stride 65 breaks bank conflict
    const int b  = blockIdx.x;                 // 256 blocks x 64 rows
    const int t  = threadIdx.x;
    const int n0 = b * 64;
    #pragma unroll
    for (int k = 0; k < 8; ++k) {
        const int idx4 = t + k * 256;
        const int r    = idx4 >> 5;
        const int c4   = idx4 & 31;
        const float4 v = ((const float4*)(mem + (size_t)(n0 + r) * DIM))[c4];
        *(ushort4*)&mf16[(size_t)(n0 + r) * DIM + c4 * 4] =
            make_ushort4(f2h(v.x), f2h(v.y), f2h(v.z), f2h(v.w));
        T[(c4 * 4 + 0) * 65 + r] = f2bf(v.x);
        T[(c4 * 4 + 1) * 65 + r] = f2bf(v.y);
        T[(c4 * 4 + 2) * 65 + r] = f2bf(v.z);
        T[(c4 * 4 + 3) * 65 + r] = f2bf(v.w);
    }
    __syncthreads();
    #pragma unroll
    for (int p = 0; p < 4; ++p) {
        const int d    = (t >> 3) + p * 32;
        const int part = t & 7;
        uint16_t tmp[8];
        #pragma unroll
        for (int e = 0; e < 8; ++e) tmp[e] = T[d * 65 + part * 8 + e];
        *(uint4*)&mhit[(size_t)d * NMEM + n0 + part * 8] = *(const uint4*)tmp;
    }
}

// ==== main attention: TQ=128, q-split fp16 QK (single product), bf16 PV ======
// R8 structure (proven 73us) minus MsLo: staging 32KB/round, QK LDS reads
// halved, QK MFMA 3x fewer. XCD pinning at validated grid=512.
template <int NCHK>
__global__ __launch_bounds__(256, 2)
void attn_kernel(const float* __restrict__ query,
                 const uint16_t* __restrict__ mf16,
                 const uint16_t* __restrict__ mhit,
                 uint16_t* __restrict__ num, float* __restrict__ den) {
    // carve: MsF16 8192 | MsT 8192 | Ps 128*72=9216 | Red 256 -> 25856 shorts
    __shared__ __align__(16) uint16_t SM[25856];   // 51712 B -> 2-3 blocks/CU
    uint16_t* MsF16 = SM;                      // [n64][d-granule^swz] fp16
    uint16_t* MsT   = SM + 8192;               // [d128][n-granule^swz] bf16
    uint16_t* Ps    = SM + 16384;              // [q128][PSTR] bf16
    float*    Red   = (float*)(SM + 25600);    // [128]

    const int tid   = threadIdx.x;
    const int wv    = tid >> 6;
    const int lane  = tid & 63;
    const int l16   = lane & 15;
    const int quad  = lane >> 4;
    const int bx    = blockIdx.x;
    constexpr int CPX = NCHK / 8;              // chunks pinned per XCD
    const int xcd   = bx & 7;
    const int j     = bx >> 3;
    const int chunk = xcd * CPX + (j % CPX);
    const int qrow  = j / CPX;                 // 0..QROWS-1
    const int q0    = qrow * TQ;
    constexpr int ITERS = NTILES_TOT / NCHK;
    const int nbase = chunk * (NMEM / NCHK);

    // ---- Q fragments for this wave's 32-query QK slice (fp16) ----
    h8v qf[2][4];
    #pragma unroll
    for (int qt = 0; qt < 2; ++qt) {
        const float* qp = query + (size_t)(q0 + wv * 32 + qt * 16 + l16) * DIM + quad * 8;
        #pragma unroll
        for (int ks = 0; ks < 4; ++ks) {
            const float4 a = *(const float4*)(qp + ks * 32);
            const float4 b = *(const float4*)(qp + ks * 32 + 4);
            h8v vh;
            vh[0] = (_Float16)a.x; vh[1] = (_Float16)a.y;
            vh[2] = (_Float16)a.z; vh[3] = (_Float16)a.w;
            vh[4] = (_Float16)b.x; vh[5] = (_Float16)b.y;
            vh[6] = (_Float16)b.z; vh[7] = (_Float16)b.w;
            qf[qt][ks] = vh;
        }
    }

    f4v oacc[8][2];                            // PV acc: 8 q-tiles x 2 d-tiles
    float dacc[8];                             // den partials: 2 qt x 4 rg
    #pragma unroll
    for (int qt = 0; qt < 8; ++qt) {
        oacc[qt][0] = (f4v){0.f, 0.f, 0.f, 0.f};
        oacc[qt][1] = (f4v){0.f, 0.f, 0.f, 0.f};
    }
    #pragma unroll
    for (int i = 0; i < 8; ++i) dacc[i] = 0.f;

    for (int it = 0; it < ITERS; ++it) {
        const int n0 = nbase + it * TN;
        __syncthreads();                       // prev iter done with tiles/Ps

        // ---- stage: 32 x 16B global_load_lds, 8 per wave ----
        #pragma unroll
        for (int ii = 0; ii < 8; ++ii) {
            const int id = wv * 8 + ii;
            if (id < 16) {                     // MsF16: 16 x 1KB
                const int s = id * 64 + lane;
                const int r = s >> 4, c = (s & 15) ^ (r & 7);
                const uint16_t* g = mf16 + (size_t)(n0 + r) * DIM + c * 8;
                __builtin_amdgcn_global_load_lds(
                    (const __attribute__((address_space(1))) void*)g,
                    (__attribute__((address_space(3))) void*)&MsF16[id * 512], 16, 0, 0);
            } else {                           // MsT: 16 x 1KB
                const int jj = id - 16;
                const int s = jj * 64 + lane;
                const int d = s >> 3, c = (s & 7) ^ (d & 7);
                const uint16_t* g = mhit + (size_t)d * NMEM + n0 + c * 8;
                __builtin_amdgcn_global_load_lds(
                    (const __attribute__((address_space(1))) void*)g,
                    (__attribute__((address_space(3))) void*)&MsT[jj * 512], 16, 0, 0);
            }
        }
        __syncthreads();                       // drain + visibility

        // ---- QK^T (q-split, fp16): wave wv computes S[its 32 q][all 64 n] --
        f4v sacc[2][4];
        #pragma unroll
        for (int qt = 0; qt < 2; ++qt)
            #pragma unroll
            for (int nt = 0; nt < 4; ++nt)
                sacc[qt][nt] = (f4v){0.f, 0.f, 0.f, 0.f};
        #pragma unroll
        for (int nt = 0; nt < 4; ++nt) {
            const int r   = nt * 16 + l16;
            const int rsw = r & 7;
            #pragma unroll
            for (int ks = 0; ks < 4; ++ks) {
                const int c = ks * 4 + quad;
                const h8v bm = *(const h8v*)&MsF16[r * DIM + ((c ^ rsw) << 3)];
                #pragma unroll
                for (int qt = 0; qt < 2; ++qt)
                    sacc[qt][nt] = __builtin_amdgcn_mfma_f32_16x16x32_f16(qf[qt][ks], bm, sacc[qt][nt], 0, 0, 0);
            }
        }

        // ---- exp + P write (bf16, num/den consistent) ----
        #pragma unroll
        for (int qt = 0; qt < 2; ++qt)
            #pragma unroll
            for (int nt = 0; nt < 4; ++nt)
                #pragma unroll
                for (int rg = 0; rg < 4; ++rg) {
                    const float p = __expf(sacc[qt][nt][rg] - SHIFT);
                    const uint16_t pb = f2bf(p);
                    dacc[qt * 4 + rg] += bf2f(pb);
                    const int qloc = wv * 32 + qt * 16 + quad * 4 + rg;
                    Ps[qloc * PSTR + nt * 16 + l16] = pb;
                }
        __syncthreads();                       // Ps visible to all waves

        // ---- PV (d-split): wave wv owns d in [wv*32, wv*32+32) ----
        #pragma unroll
        for (int ksP = 0; ksP < 2; ++ksP) {
            s8v bt[2];
            #pragma unroll
            for (int dt = 0; dt < 2; ++dt) {
                const int d  = wv * 32 + dt * 16 + l16;
                const int cg = ksP * 4 + quad;
                bt[dt] = *(const s8v*)&MsT[d * TN + ((cg ^ (d & 7)) << 3)];
            }
            #pragma unroll
            for (int qt = 0; qt < 8; ++qt) {
                const int q = qt * 16 + l16;
                const s8v pf = *(const s8v*)&Ps[q * PSTR + ksP * 32 + quad * 8];
                oacc[qt][0] = __builtin_amdgcn_mfma_f32_16x16x32_bf16(pf, bt[0], oacc[qt][0], 0, 0, 0);
                oacc[qt][1] = __builtin_amdgcn_mfma_f32_16x16x32_bf16(pf, bt[1], oacc[qt][1], 0, 0, 0);
            }
        }
    }

    // ---- denominator: reduce over l16 (each q lives in exactly one wave) ----
    #pragma unroll
    for (int m = 1; m <= 8; m <<= 1)
        #pragma unroll
        for (int i = 0; i < 8; ++i)
            dacc[i] += __shfl_xor(dacc[i], m, 64);
    __syncthreads();                           // loop done; SM reusable
    if (l16 == 0) {
        #pragma unroll
        for (int qt = 0; qt < 2; ++qt)
            #pragma unroll
            for (int rg = 0; rg < 4; ++rg)
                Red[wv * 32 + qt * 16 + quad * 4 + rg] = dacc[qt * 4 + rg];
    }
    // ---- O merge into LDS (bf16) for coalesced stores ----
    uint16_t* Obuf = SM;                       // 128 q x 128 d x 2B = 32 KB
    #pragma unroll
    for (int qt = 0; qt < 8; ++qt)
        #pragma unroll
        for (int dt = 0; dt < 2; ++dt)
            #pragma unroll
            for (int rg = 0; rg < 4; ++rg) {
                const int qq = qt * 16 + quad * 4 + rg;
                const int dd = wv * 32 + dt * 16 + l16;
                Obuf[qq * DIM + dd] = f2bf(oacc[qt][dt][rg]);
            }
    __syncthreads();
    if (tid < TQ) den[chunk * NQ_TOT + q0 + tid] = Red[tid];
    {
        uint4* dst = (uint4*)(num + ((size_t)chunk * NQ_TOT + q0) * DIM);
        const uint4* src = (const uint4*)Obuf;
        #pragma unroll
        for (int k = 0; k < 8; ++k) {
            const int f = tid + k * 256;       // 2048 uint4s (32 KB)
            dst[f] = src[f];
        }
    }
}

// ============ final reduce over chunks + normalize ============
template <int NCHK>
__global__ __launch_bounds__(256)
void reduce_kernel(const uint16_t* __restrict__ num, const float* __restrict__ den,
                   float* __restrict__ out) {
    const int f = blockIdx.x * 256 + threadIdx.x;   // 65536 groups of 4
    const int q = f >> 5;
    float4 ns = make_float4(0.f, 0.f, 0.f, 0.f);
    float ds = 0.f;
    #pragma unroll
    for (int c = 0; c < NCHK; ++c) {
        const ushort4 v = ((const ushort4*)num)[c * (NQ_TOT * DIM / 4) + f];
        ns.x += bf2f(v.x); ns.y += bf2f(v.y); ns.z += bf2f(v.z); ns.w += bf2f(v.w);
        ds += den[c * NQ_TOT + q];
    }
    const float inv = 1.0f / ds;
    ((float4*)out)[f] = make_float4(ns.x * inv, ns.y * inv, ns.z * inv, ns.w * inv);
}

// ============ fallback (round-1 fp32 kernel) if ws too small ============
#define FTQ 8
#define FTN 64
#define FNTILES (NMEM / FTN)
#define FBLOCK 512
#define MPAD 132
#define PPAD 68

__global__ __launch_bounds__(FBLOCK, 2)
void sparse_attn_fp32(const float* __restrict__ query,
                      const float* __restrict__ memory,
                      float* __restrict__ out) {
    __shared__ float Qs[FTQ * MPAD];
    __shared__ float Ms[FTN * MPAD];
    __shared__ float Psh[FTQ * PPAD];
    __shared__ float Rd[FTQ * PPAD];
    const int tid = threadIdx.x;
    const int q = tid & 7, rest = tid >> 3;
    const int ng = rest, dg = rest & 31, half = rest >> 5;
    const long q0 = (long)blockIdx.x * FTQ;
    if (tid < FTQ * DIM / 4) {
        const float4 v = ((const float4*)(query + q0 * DIM))[tid];
        *(float4*)&Qs[(tid >> 5) * MPAD + ((tid & 31) << 2)] = v;
    }
    float4 pf[4];
    {
        const float4* msrc = (const float4*)memory;
        #pragma unroll
        for (int k = 0; k < 4; ++k) pf[k] = msrc[tid + k * FBLOCK];
    }
    float4 acc = make_float4(0.f, 0.f, 0.f, 0.f);
    float l_part = 0.f;
    for (int t = 0; t < FNTILES; ++t) {
        __syncthreads();
        #pragma unroll
        for (int k = 0; k < 4; ++k) {
            const int f4 = tid + k * FBLOCK;
            *(float4*)&Ms[(f4 >> 5) * MPAD + ((f4 & 31) << 2)] = pf[k];
        }
        __syncthreads();
        if (t + 1 < FNTILES) {
            const float4* msrc = (const float4*)(memory + (long)(t + 1) * FTN * DIM);
            #pragma unroll
            for (int k = 0; k < 4; ++k) pf[k] = msrc[tid + k * FBLOCK];
        }
        float4 s4 = make_float4(0.f, 0.f, 0.f, 0.f);
        const float* qrow = &Qs[q * MPAD];
        const float* mrow = &Ms[ng * MPAD];
        #pragma unroll
        for (int jj = 0; jj < 32; ++jj) {
            const float4 qv = *(const float4*)&qrow[jj * 4];
            const float4 mv = *(const float4*)&mrow[jj * 4];
            s4.x += qv.x * mv.x; s4.y += qv.y * mv.y;
            s4.z += qv.z * mv.z; s4.w += qv.w * mv.w;
        }
        const float p = __expf(((s4.x + s4.y) + (s4.z + s4.w)) - SHIFT);
        Psh[q * PPAD + ng] = p;
        l_part += p;
        __syncthreads();
        #pragma unroll
        for (int n = 0; n < 32; ++n) {
            const int nn = half * 32 + n;
            const float pw = Psh[q * PPAD + nn];
            const float4 mv = *(const float4*)&Ms[nn * MPAD + dg * 4];
            acc.x += pw * mv.x; acc.y += pw * mv.y;
            acc.z += pw * mv.z; acc.w += pw * mv.w;
        }
    }
    __syncthreads();
    Rd[q * PPAD + rest] = l_part;
    if (half == 1) *(float4*)&Ms[q * MPAD + dg * 4] = acc;
    __syncthreads();
    if (half == 0) {
        const float4 o2 = *(const float4*)&Ms[q * MPAD + dg * 4];
        float l = 0.f;
        #pragma unroll 8
        for (int i = 0; i < 64; ++i) l += Rd[q * PPAD + i];
        const float inv = 1.0f / l;
        float4 o;
        o.x = (acc.x + o2.x) * inv; o.y = (acc.y + o2.y) * inv;
        o.z = (acc.z + o2.z) * inv; o.w = (acc.w + o2.w) * inv;
        *(float4*)(out + (q0 + q) * DIM + dg * 4) = o;
    }
}

extern "C" void kernel_launch(void* const* d_in, const int* in_sizes, int n_in,
                              void* d_out, int out_size, void* d_ws, size_t ws_size,
                              hipStream_t stream) {
    const float* query  = (const float*)d_in[0];
    const float* memory = (const float*)d_in[1];
    float* out = (float*)d_out;
    if (ws_size >= WS_NEED(16)) {
        uint16_t* mf16 = (uint16_t*)((char*)d_ws + OFF_MF16);
        uint16_t* mhit = (uint16_t*)((char*)d_ws + OFF_MHIT);
        uint16_t* num  = (uint16_t*)((char*)d_ws + OFF_NUM);
        convert_kernel<<<NMEM / 64, 256, 0, stream>>>(memory, mf16, mhit);
        if (ws_size >= WS_NEED(32)) {
            float* den = (float*)((char*)d_ws + OFF_DEN(32));
            attn_kernel<32><<<QROWS * 32, 256, 0, stream>>>(query, mf16, mhit, num, den);
            reduce_kernel<32><<<NQ_TOT * DIM / 4 / 256, 256, 0, stream>>>(num, den, out);
        } else {
            float* den = (float*)((char*)d_ws + OFF_DEN(16));
            attn_kernel<16><<<QROWS * 16, 256, 0, stream>>>(query, mf16, mhit, num, den);
            reduce_kernel<16><<<NQ_TOT * DIM / 4 / 256, 256, 0, stream>>>(num, den, out);
        }
    } else {
        sparse_attn_fp32<<<NQ_TOT / FTQ, FBLOCK, 0, stream>>>(query, memory, out);
    }
}